// Round 13
// baseline (1689.173 us; speedup 1.0000x reference)
//
#include <hip/hip_runtime.h>

// Problem constants
#define B_    64
#define T_    512
#define KDIM  1024
#define HID_  1024

// Tile sizes
#define BM 64    // t-chunk per block iteration (8 chunks)
#define BN 64    // h-tile per block
#define BK 32    // two numpy 16-k blocks per slice
#define LDA 36   // padded LDS row (A conflict-free, B 2-way-free, 16B aligned)
#define NSL 256  // total slices = (T_/BM)*(KDIM/BK)
#define SPC 32   // slices per chunk = KDIM/BK

// f32 correctly rounded from python float math.exp(-1.0/20.0)
#define ALPHA_F 0.95122942450071400909f

typedef float v4f __attribute__((ext_vector_type(4)));
typedef float v2f __attribute__((ext_vector_type(2)));

// Bit-faithful replication of the harness numpy f32 reference (einsum
// optimize=False, SSE baseline): per output element 4 f32 accumulator lanes
// (lane l sums k = l mod 4), per-16k-block chained adds == descending-q
// accumulation (q=3..0), blocks ascending, mul/add separately rounded (no
// FMA), hadd tree (l0+l1)+(l2+l3), one f32 bias add; f32 scan. Chain
// byte-identical to R6..R12 (all PASSED).
//
// R13 vs R12 (1.50 ms): the wall is the LDS-issue floor (64 b128/wave/slice
// x 12 cyc = 1.31 ms chip-wide) — prefetch/dbuf attacked stall, not the pipe.
// Fix: LANE-SPLIT 8x4 micro-tile. numpy's 4 accumulator lanes are independent
// chains until the final hadd, so thread-half 0 (tid<128) carries lanes {0,1}
// and half 1 carries lanes {2,3}: acc regs stay at 64/thread (the 8x4 full
// tile's 128 acc regs spilled in R8/R9), while LDS bytes/MAC drop 2.0 -> 1.5
// via ds_read_b64 fragments (96 b64 x ~6 cyc = 576 cyc/wave/slice vs 768).
// The hadd is reassembled in-place in Ism: half1 writes s23, barrier, half0
// computes (s01+s23)+bias — exact tree preserved.
__global__ __launch_bounds__(256, 2) void snn_np_ls(
    const float* __restrict__ x,     // [B,T,K] f32
    const float* __restrict__ W,     // [H,K] f32
    const float* __restrict__ bias,  // [H] f32
    float* __restrict__ spikes,      // [B,T,H] f32 out
    float* __restrict__ memf)        // [B,H] f32 out
{
#pragma clang fp contract(off)       // numpy SSE path has no FMA: mul+add only
    __shared__ float As[BM * LDA];        // 9.0 KB
    __shared__ float Bs[BN * LDA];        // 9.0 KB
    __shared__ float Ism[BM * (BN + 1)];  // 16.3 KB
    __shared__ float bsh[BN];

    const int tid = threadIdx.x;
    const int bb  = blockIdx.x;          // batch index
    const int h0  = blockIdx.y * BN;     // h tile origin

    const int tx   = tid & 15;           // h micro-index (4 cols, stride 16)
    const int ry   = (tid >> 4) & 7;     // t micro-index (8 rows, stride 8)
    const int half = tid >> 7;           // 0: numpy lanes {0,1}; 1: lanes {2,3}

    const int sr0 = tid >> 3;            // staging rows 0..31
    const int sr1 = 32 + sr0;            // staging rows 32..63
    const int sc  = (tid & 7) << 2;      // staging col 0,4,..,28

    const float* xb = x + (size_t)bb * T_ * KDIM;
    const float* Wb = W + (size_t)h0 * KDIM;

    if (tid < BN) bsh[tid] = bias[h0 + tid];

    float mem = 0.0f;                    // threads 0..63 carry h = h0+tid

    // prefetch slice 0 (chunk 0, k0 = 0) into registers
    float4 pa0 = *(const float4*)&xb[(size_t)sr0 * KDIM + sc];
    float4 pa1 = *(const float4*)&xb[(size_t)sr1 * KDIM + sc];
    float4 pw0 = *(const float4*)&Wb[(size_t)sr0 * KDIM + sc];
    float4 pw1 = *(const float4*)&Wb[(size_t)sr1 * KDIM + sc];

    for (int c = 0; c < T_ / BM; ++c) {
        // this thread's 2 numpy lanes for 8x4 elements: p[j][i] = (l0,l1) or (l2,l3)
        v2f p[8][4];
#pragma unroll
        for (int j = 0; j < 8; ++j)
#pragma unroll
            for (int i = 0; i < 4; ++i) p[j][i] = (v2f)(0.0f);

        for (int s = 0; s < SPC; ++s) {
            __syncthreads();   // prev slice's As/Bs readers done (+ bsh/Ism users)
            // commit prefetched slice g = c*SPC+s to LDS
            *(float4*)&As[sr0 * LDA + sc] = pa0;
            *(float4*)&As[sr1 * LDA + sc] = pa1;
            *(float4*)&Bs[sr0 * LDA + sc] = pw0;
            *(float4*)&Bs[sr1 * LDA + sc] = pw1;
            // issue slice g+1 loads; latency hides under compute below
            const int g1 = c * SPC + s + 1;
            if (g1 < NSL) {
                const int nt0 = (g1 >> 5) * BM;
                const int nk  = (g1 & 31) << 5;
                pa0 = *(const float4*)&xb[(size_t)(nt0 + sr0) * KDIM + nk + sc];
                pa1 = *(const float4*)&xb[(size_t)(nt0 + sr1) * KDIM + nk + sc];
                pw0 = *(const float4*)&Wb[(size_t)sr0 * KDIM + nk + sc];
                pw1 = *(const float4*)&Wb[(size_t)sr1 * KDIM + nk + sc];
            }
            __syncthreads();   // LDS slice ready
            // two numpy 16-k blocks, ascending; q = 3,2,1,0 within each.
            // This thread accumulates its 2 lanes: k = 16kb + 4q + 2*half {+0,+1}.
            // Per lane the add order is q=3,2,1,0 per block, blocks ascending —
            // bitwise equal to numpy's chained a0b0+(a1b1+(a2b2+(a3b3+acc))).
#pragma unroll
            for (int kb = 0; kb < 2; ++kb) {
#pragma unroll
                for (int q = 3; q >= 0; --q) {
                    const int qc = (kb << 4) + (q << 2) + (half << 1);
                    v2f a2[8], b2[4];
#pragma unroll
                    for (int j = 0; j < 8; ++j)
                        a2[j] = *(const v2f*)&As[(ry + 8 * j) * LDA + qc];
#pragma unroll
                    for (int i = 0; i < 4; ++i)
                        b2[i] = *(const v2f*)&Bs[(tx + 16 * i) * LDA + qc];
#pragma unroll
                    for (int j = 0; j < 8; ++j)
#pragma unroll
                        for (int i = 0; i < 4; ++i) {
                            const v2f m = a2[j] * b2[i];   // rounded muls
                            p[j][i] = p[j][i] + m;         // rounded adds
                        }
                }
            }
        }

        // combine halves in place in Ism: numpy hadd (l0+l1)+(l2+l3), + bias.
        if (half) {
#pragma unroll
            for (int j = 0; j < 8; ++j)
#pragma unroll
                for (int i = 0; i < 4; ++i)
                    Ism[(ry + 8 * j) * (BN + 1) + tx + 16 * i] =
                        p[j][i].x + p[j][i].y;             // s23 = l2 + l3
        }
        __syncthreads();
        if (!half) {
#pragma unroll
            for (int j = 0; j < 8; ++j)
#pragma unroll
                for (int i = 0; i < 4; ++i) {
                    const int cell = (ry + 8 * j) * (BN + 1) + tx + 16 * i;
                    const float s01 = p[j][i].x + p[j][i].y;   // l0 + l1
                    const float s23 = Ism[cell];
                    Ism[cell] = (s01 + s23) + bsh[tx + 16 * i];
                }
        }
        __syncthreads();

        // f32 LIF scan over this chunk; one thread per h.
        if (tid < BN) {
            const size_t srow0 = ((size_t)(bb * T_ + c * BM)) * HID_ + h0 + tid;
#pragma unroll 4
            for (int t = 0; t < BM; ++t) {
                const float It = Ism[t * (BN + 1) + tid];
                const float am = ALPHA_F * mem;   // rounded mul
                mem = am + It;                    // rounded add
                const bool fire = (mem >= 1.0f);
                spikes[srow0 + (size_t)t * HID_] = fire ? 1.0f : 0.0f;
                if (fire) mem = 0.0f;
            }
        }
        // next chunk's first top-of-slice barrier orders the scan's Ism reads
        // before the next combine's Ism writes (staging only touches As/Bs).
    }

    if (tid < BN) memf[(size_t)bb * HID_ + h0 + tid] = mem;
}

extern "C" void kernel_launch(void* const* d_in, const int* in_sizes, int n_in,
                              void* d_out, int out_size, void* d_ws, size_t ws_size,
                              hipStream_t stream) {
    const float* x    = (const float*)d_in[0];   // [B,T,K] f32
    const float* W    = (const float*)d_in[1];   // [H,K] f32
    const float* bias = (const float*)d_in[2];   // [H] f32
    float* out    = (float*)d_out;
    float* spikes = out;                          // [B,T,H]
    float* memf   = out + (size_t)B_ * T_ * HID_; // [B,H]

    dim3 grid(B_, HID_ / BN);   // 64 x 16 = 1024 blocks
    snn_np_ls<<<grid, dim3(256), 0, stream>>>(x, W, bias, spikes, memf);
}